// Round 10
// baseline (2019.307 us; speedup 1.0000x reference)
//
#include <hip/hip_runtime.h>

#define N_NODES 100000
#define N_EDGES 3200000
#define NFEAT 512
#define NHID 256
#define NCLASS 64
#define KHOPS 10
#define SCAN_B 391   // ceil(N_NODES/256)

// radix-partition CSR build
#define NBSHIFT 9
#define NBUCK 196    // ceil(N_NODES/512)
#define BCAP 20480   // >= max bucket size (avg 16.3K, sigma ~128)
#define TILE 4096

// feature slicing for L2-resident propagation
#define SW 16        // slice width (32B/node rows)
#define NSL 4        // NCLASS / SW

typedef __bf16 bf16x8 __attribute__((ext_vector_type(8)));
typedef __bf16 bf16x4 __attribute__((ext_vector_type(4)));
typedef float f32x4 __attribute__((ext_vector_type(4)));

// ---------------- preprocessing ----------------

__global__ __launch_bounds__(256) void zero_deg_kernel(int* __restrict__ deg, int* __restrict__ bcursor) {
    int i = blockIdx.x * 256 + threadIdx.x;
    if (i < N_NODES) deg[i] = 0;
    if (blockIdx.x == 0 && threadIdx.x < NBUCK) bcursor[threadIdx.x] = 0;
}

// fallback-path degree count (global atomics)
__global__ __launch_bounds__(256) void deg_kernel(const int* __restrict__ ei, int* __restrict__ deg) {
    int e = blockIdx.x * 256 + threadIdx.x;
    if (e < N_EDGES) atomicAdd(&deg[ei[N_EDGES + e]], 1);
}

__global__ __launch_bounds__(256) void dinv_kernel(const int* __restrict__ deg, float* __restrict__ dinv) {
    int i = blockIdx.x * 256 + threadIdx.x;
    if (i < N_NODES) dinv[i] = rsqrtf((float)(deg[i] + 1)); // +1 self-loop
}

// ---- radix pass 1: partition edges by dst>>9 with per-block contiguous runs ----

__global__ __launch_bounds__(256) void radix1_kernel(const int* __restrict__ ei,
                                                     int* __restrict__ bcursor,
                                                     int2* __restrict__ breg) {
    __shared__ int2 stage[TILE];
    __shared__ int hist[NBUCK];
    __shared__ int base[NBUCK];
    __shared__ int offs[NBUCK];
    int t = threadIdx.x;
    int e0 = blockIdx.x * TILE;
    int n = N_EDGES - e0; if (n > TILE) n = TILE;
    for (int i = t; i < NBUCK; i += 256) { hist[i] = 0; offs[i] = 0; }
    __syncthreads();
    for (int i = t; i < n; i += 256) {
        int s = ei[e0 + i];
        int d = ei[N_EDGES + e0 + i];
        stage[i] = make_int2(s, d);
        atomicAdd(&hist[d >> NBSHIFT], 1);
    }
    __syncthreads();
    for (int i = t; i < NBUCK; i += 256)
        if (hist[i]) base[i] = atomicAdd(&bcursor[i], hist[i]);
    __syncthreads();
    for (int i = t; i < n; i += 256) {
        int2 e = stage[i];
        int b = e.y >> NBSHIFT;
        int slot = base[b] + atomicAdd(&offs[b], 1);
        if (slot < BCAP) breg[(size_t)b * BCAP + slot] = e;
    }
}

// ---- per-bucket degree count in LDS (no global atomics) + fused dinv ----

__global__ __launch_bounds__(256) void bucket_deg_kernel(const int2* __restrict__ breg,
                                                         const int* __restrict__ bcursor,
                                                         int* __restrict__ deg,
                                                         float* __restrict__ dinv) {
    __shared__ int cnt[512];
    int b = blockIdx.x;
    int t = threadIdx.x;
    cnt[t] = 0; cnt[t + 256] = 0;
    __syncthreads();
    int n = bcursor[b]; if (n > BCAP) n = BCAP;
    const int2* bp = breg + (size_t)b * BCAP;
    for (int i = t; i < n; i += 256)
        atomicAdd(&cnt[bp[i].y & 511], 1);
    __syncthreads();
    int d0 = b << NBSHIFT;
    for (int j = t; j < 512; j += 256) {
        int i = d0 + j;
        if (i < N_NODES) {
            int d = cnt[j];
            deg[i] = d;
            dinv[i] = rsqrtf((float)(d + 1)); // +1 self-loop
        }
    }
}

// ---- hierarchical scan of (deg[i]+1) ----

__global__ __launch_bounds__(256) void scan1_kernel(const int* __restrict__ deg, int* __restrict__ partial) {
    __shared__ int red[256];
    int t = threadIdx.x;
    int i = blockIdx.x * 256 + t;
    red[t] = (i < N_NODES) ? deg[i] + 1 : 0;
    __syncthreads();
    for (int off = 128; off > 0; off >>= 1) {
        if (t < off) red[t] += red[t + off];
        __syncthreads();
    }
    if (t == 0) partial[blockIdx.x] = red[0];
}

__global__ __launch_bounds__(512) void scan2_kernel(int* __restrict__ partial) {
    __shared__ int s[512];
    int t = threadIdx.x;
    int v = (t < SCAN_B) ? partial[t] : 0;
    s[t] = v;
    __syncthreads();
    for (int off = 1; off < 512; off <<= 1) {
        int add = (t >= off) ? s[t - off] : 0;
        __syncthreads();
        s[t] += add;
        __syncthreads();
    }
    if (t < SCAN_B) partial[t] = s[t] - v; // exclusive
}

__global__ __launch_bounds__(256) void scan3_kernel(const int* __restrict__ deg,
                                                    const int* __restrict__ partial,
                                                    int* __restrict__ row_ptr,
                                                    int* __restrict__ cursor) {
    __shared__ int s[256];
    int t = threadIdx.x;
    int i = blockIdx.x * 256 + t;
    int v = (i < N_NODES) ? deg[i] + 1 : 0;
    s[t] = v;
    __syncthreads();
    for (int off = 1; off < 256; off <<= 1) {
        int add = (t >= off) ? s[t - off] : 0;
        __syncthreads();
        s[t] += add;
        __syncthreads();
    }
    int excl = s[t] - v + partial[blockIdx.x];
    if (i < N_NODES) {
        row_ptr[i] = excl;
        cursor[i] = excl;
        if (i == N_NODES - 1) row_ptr[N_NODES] = excl + v;
    }
}

// ---- radix pass 2: bucket -> final CSR via LDS cursors; self-loop at segment head ----

__global__ __launch_bounds__(256) void radix2_kernel(const int2* __restrict__ breg,
                                                     const int* __restrict__ bcursor,
                                                     const int* __restrict__ row_ptr,
                                                     int* __restrict__ esrc) {
    __shared__ int lcur[512];
    int b = blockIdx.x;
    int t = threadIdx.x;
    int d0 = b << NBSHIFT;
    int nn = N_NODES - d0; if (nn > 512) nn = 512;
    for (int j = t; j < nn; j += 256) {
        int rp = row_ptr[d0 + j];
        lcur[j] = rp + 1;
        esrc[rp] = d0 + j;        // self-loop
    }
    __syncthreads();
    int cnt = bcursor[b]; if (cnt > BCAP) cnt = BCAP;
    const int2* bp = breg + (size_t)b * BCAP;
    for (int i = t; i < cnt; i += 256) {
        int2 e = bp[i];
        int p = atomicAdd(&lcur[e.y - d0], 1);
        esrc[p] = e.x;
    }
}

// fallback CSR fill (used only if workspace too small for radix buffer)
__global__ __launch_bounds__(256) void fill_kernel(const int* __restrict__ ei,
                                                   int* __restrict__ cursor,
                                                   int* __restrict__ esrc) {
    int e = blockIdx.x * 256 + threadIdx.x;
    if (e < N_EDGES) {
        int s = ei[e], d = ei[N_EDGES + e];
        int p = atomicAdd(&cursor[d], 1);
        esrc[p] = s;
    } else if (e < N_EDGES + N_NODES) {
        int i = e - N_EDGES;
        int p = atomicAdd(&cursor[i], 1);
        esrc[p] = i; // self-loop
    }
}

// ---------------- weight prep: W1^T, W2^T in bf16 ----------------

__global__ __launch_bounds__(256) void wprep_kernel(const float* __restrict__ W1,
                                                    const float* __restrict__ W2,
                                                    __bf16* __restrict__ w1t,
                                                    __bf16* __restrict__ w2t) {
    int i = blockIdx.x * 256 + threadIdx.x;
    if (i < NFEAT * NHID) {
        int n = i >> 9, k = i & 511;           // w1t[n][k], k<512
        w1t[i] = (__bf16)W1[k * NHID + n];
    } else {
        int j = i - NFEAT * NHID;
        if (j < NHID * NCLASS) {
            int n = j >> 8, k = j & 255;       // w2t[n][k], k<256
            w2t[j] = (__bf16)W2[k * NCLASS + n];
        }
    }
}

// ---------------- fused MLP via bf16 MFMA — MT=128, 8 waves, staged + x-prefetch ----------------

#define MT 128
#define KC 64
#define XP 72
#define WP 72
#define HP 264

__global__ __launch_bounds__(512, 4) void mlp_kernel(const float* __restrict__ x,
                                                     const __bf16* __restrict__ w1t,
                                                     const float* __restrict__ b1,
                                                     const __bf16* __restrict__ w2t,
                                                     const float* __restrict__ b2,
                                                     const float* __restrict__ dinv,
                                                     __bf16* __restrict__ u0) {    // [NSL][K+1][N][SW]
    __shared__ char smem[67584] __attribute__((aligned(16)));
    __bf16* xs  = (__bf16*)smem;              // 128*72*2 = 18432 B
    __bf16* wt  = (__bf16*)(smem + 18432);    // 256*72*2 = 36864 B
    __bf16* h1s = (__bf16*)smem;              // 128*264*2 = 67584 B (after barrier)

    int t = threadIdx.x;
    int wv = t >> 6, lane = t & 63;
    int lrow = lane & 15;
    int quad = lane >> 4;
    int row0 = blockIdx.x * MT;
    int wm = (wv >> 2) * 64;   // layer1 row group (0/64)
    int wn = (wv & 3) * 64;    // layer1 col group (0/64/128/192)

    // x staging map: j = it*512+t -> row r=j>>3 (0..127), col-octet c8=j&7
    const float* xpt[2];
    int xr[2], xc8[2];
    #pragma unroll
    for (int it = 0; it < 2; ++it) {
        int j = it * 512 + t;
        int r = j >> 3, c8 = j & 7;
        int rr = row0 + r; if (rr >= N_NODES) rr = N_NODES - 1;
        xpt[it] = &x[(size_t)rr * NFEAT + c8 * 8];
        xr[it] = r; xc8[it] = c8;
    }
    // prologue: prefetch chunk 0
    float4 px[4];
    px[0] = *(const float4*)(xpt[0]);
    px[1] = *(const float4*)(xpt[0] + 4);
    px[2] = *(const float4*)(xpt[1]);
    px[3] = *(const float4*)(xpt[1] + 4);

    f32x4 acc[4][4] = {};
    #pragma unroll 1
    for (int kc = 0; kc < NFEAT; kc += KC) {
        __syncthreads();   // previous chunk's frag reads done; LDS free
        // write prefetched x (cvt fp32->bf16) into xs
        #pragma unroll
        for (int it = 0; it < 2; ++it) {
            float4 v0 = px[it * 2], v1 = px[it * 2 + 1];
            bf16x8 o = { (__bf16)v0.x, (__bf16)v0.y, (__bf16)v0.z, (__bf16)v0.w,
                         (__bf16)v1.x, (__bf16)v1.y, (__bf16)v1.z, (__bf16)v1.w };
            *(bf16x8*)&xs[xr[it] * XP + xc8[it] * 8] = o;
        }
        // stage w1t chunk (L2-hot) directly
        #pragma unroll
        for (int it = 0; it < 4; ++it) {
            int j = it * 512 + t;
            int n = j >> 3, c8 = j & 7;
            *(bf16x8*)&wt[n * WP + c8 * 8] = *(const bf16x8*)&w1t[(size_t)n * NFEAT + kc + c8 * 8];
        }
        __syncthreads();   // chunk kc staged
        // prefetch next chunk's x (HBM latency hides under the MFMAs below)
        if (kc + KC < NFEAT) {
            px[0] = *(const float4*)(xpt[0] + kc + KC);
            px[1] = *(const float4*)(xpt[0] + kc + KC + 4);
            px[2] = *(const float4*)(xpt[1] + kc + KC);
            px[3] = *(const float4*)(xpt[1] + kc + KC + 4);
        }
        #pragma unroll
        for (int ks = 0; ks < 2; ++ks) {
            int kof = ks * 32 + quad * 8;
            bf16x8 a[4], b[4];
            #pragma unroll
            for (int mt = 0; mt < 4; ++mt)
                a[mt] = *(const bf16x8*)&xs[(wm + mt * 16 + lrow) * XP + kof];
            #pragma unroll
            for (int nt = 0; nt < 4; ++nt)
                b[nt] = *(const bf16x8*)&wt[(wn + nt * 16 + lrow) * WP + kof];
            #pragma unroll
            for (int mt = 0; mt < 4; ++mt)
                #pragma unroll
                for (int nt = 0; nt < 4; ++nt)
                    acc[mt][nt] = __builtin_amdgcn_mfma_f32_16x16x32_bf16(a[mt], b[nt], acc[mt][nt], 0, 0, 0);
        }
    }
    __syncthreads();   // K-loop done; staging buffers free for h1s
    // layer1 epilogue: bias + ReLU -> bf16 h1 in LDS
    #pragma unroll
    for (int nt = 0; nt < 4; ++nt) {
        int coln = wn + nt * 16 + lrow;
        float bb = b1[coln];
        #pragma unroll
        for (int mt = 0; mt < 4; ++mt) {
            int rbase = wm + mt * 16 + quad * 4;
            #pragma unroll
            for (int r = 0; r < 4; ++r) {
                float v = acc[mt][nt][r] + bb;
                h1s[(rbase + r) * HP + coln] = (__bf16)fmaxf(v, 0.f);
            }
        }
    }
    __syncthreads();
    // layer 2
    int rg = (wv >> 1) * 32;
    int cg = (wv & 1) * 32;
    f32x4 acc2[2][2] = {};
    #pragma unroll
    for (int ks = 0; ks < 8; ++ks) {
        int kof = ks * 32 + quad * 8;
        bf16x8 a2[2], bv[2];
        #pragma unroll
        for (int m2 = 0; m2 < 2; ++m2)
            a2[m2] = *(const bf16x8*)&h1s[(rg + m2 * 16 + lrow) * HP + kof];
        #pragma unroll
        for (int nt = 0; nt < 2; ++nt)
            bv[nt] = *(const bf16x8*)&w2t[(size_t)(cg + nt * 16 + lrow) * NHID + kof];
        #pragma unroll
        for (int m2 = 0; m2 < 2; ++m2)
            #pragma unroll
            for (int nt = 0; nt < 2; ++nt)
                acc2[m2][nt] = __builtin_amdgcn_mfma_f32_16x16x32_bf16(a2[m2], bv[nt], acc2[m2][nt], 0, 0, 0);
    }
    const size_t sls = (size_t)(KHOPS + 1) * N_NODES * SW;  // slice plane-set stride
    #pragma unroll
    for (int m2 = 0; m2 < 2; ++m2) {
        #pragma unroll
        for (int nt = 0; nt < 2; ++nt) {
            int coln = cg + nt * 16 + lrow;
            float bb = b2[coln];
            int sl = coln >> 4, cin = coln & 15;
            #pragma unroll
            for (int r = 0; r < 4; ++r) {
                int row = row0 + rg + m2 * 16 + quad * 4 + r;
                if (row < N_NODES) {
                    float v = acc2[m2][nt][r] + bb;
                    u0[(size_t)sl * sls + (size_t)row * SW + cin] = (__bf16)(dinv[row] * v);
                }
            }
        }
    }
}

// ---------------- propagation: slice-serialized, L2-resident 3.2MB planes ----------------
// One dispatch = one (slice, hop): random-gather target is a single [N][16] bf16 plane
// (3.2MB -> fits every XCD's 4MiB L2). 4 lanes/edge x 8B loads (32B/edge, 1 transaction),
// 16 edges/iter; butterfly xor 4/8/16/32 (16 shfl); nontemporal esrc loads + uout stores
// keep the streams from evicting the resident plane.

__global__ __launch_bounds__(256) void prop_kernel(const __bf16* __restrict__ uin,   // [N][SW]
                                                   __bf16* __restrict__ uout,        // [N][SW]
                                                   const int* __restrict__ row_ptr,
                                                   const int* __restrict__ esrc,
                                                   const float* __restrict__ dinv) {
    int node = blockIdx.x * 4 + (threadIdx.x >> 6);
    int lane = threadIdx.x & 63;
    int eslot = lane >> 2, q = lane & 3;     // q: byte-quarter of the 32B row
    int beg = row_ptr[node], end = row_ptr[node + 1];
    const unsigned long long* ub = (const unsigned long long*)uin;  // node stride 4 u64 (32B)
    float acc[4] = {};
    int nit = (end - beg + 15) >> 4;
    #pragma unroll 2
    for (int it = 0; it < nit; ++it) {
        int e = beg + it * 16 + eslot;
        int ec = min(e, end - 1);            // clamp (self-loop => end>beg)
        int s = __builtin_nontemporal_load(&esrc[ec]);
        float m = (e < end) ? 1.f : 0.f;
        unsigned long long v = ub[(size_t)s * 4 + q];
        unsigned lo = (unsigned)v, hi = (unsigned)(v >> 32);
        acc[0] = fmaf(m, __int_as_float(lo << 16), acc[0]);
        acc[1] = fmaf(m, __int_as_float(lo & 0xffff0000u), acc[1]);
        acc[2] = fmaf(m, __int_as_float(hi << 16), acc[2]);
        acc[3] = fmaf(m, __int_as_float(hi & 0xffff0000u), acc[3]);
    }
    #pragma unroll
    for (int j = 0; j < 4; ++j) {
        acc[j] += __shfl_xor(acc[j], 4);
        acc[j] += __shfl_xor(acc[j], 8);
        acc[j] += __shfl_xor(acc[j], 16);
        acc[j] += __shfl_xor(acc[j], 32);
    }
    if (eslot == 0) {                        // lanes 0-3: lane q owns feats q*4..q*4+3
        float di = dinv[node];
        float d2 = di * di;
        union { __bf16 b[4]; unsigned long long u; } pk;
        #pragma unroll
        for (int j = 0; j < 4; ++j) pk.b[j] = (__bf16)(d2 * acc[j]);
        __builtin_nontemporal_store(pk.u, &((unsigned long long*)uout)[(size_t)node * 4 + q]);
    }
}

// ---------------- finale: deferred GPR taps + log_softmax, fused ----------------
// ubuf layout [NSL][K+1][N][SW]; thread (node,j): slice j>>4, feat-in-slice j&15.

__global__ __launch_bounds__(256) void finale_kernel(const __bf16* __restrict__ ubuf,
                                                     const float* __restrict__ dinv,
                                                     const float* __restrict__ temp,
                                                     float* __restrict__ out) {
    int node = blockIdx.x * 4 + (threadIdx.x >> 6);
    int j = threadIdx.x & 63;
    int sl = j >> 4, cin = j & 15;
    const unsigned short* ub = (const unsigned short*)ubuf
        + (size_t)sl * (KHOPS + 1) * N_NODES * SW + (size_t)node * SW + cin;
    float acc = 0.f;
    #pragma unroll
    for (int k = 0; k <= KHOPS; ++k) {
        unsigned short us = __builtin_nontemporal_load(ub + (size_t)k * N_NODES * SW);
        acc = fmaf(temp[k], __int_as_float((unsigned)us << 16), acc);
    }
    float v = acc / dinv[node];   // h = u / dinv
    float m = v;
    #pragma unroll
    for (int o = 32; o > 0; o >>= 1) m = fmaxf(m, __shfl_xor(m, o));
    float ex = expf(v - m);
    float s = ex;
    #pragma unroll
    for (int o = 32; o > 0; o >>= 1) s += __shfl_xor(s, o);
    out[(size_t)node * 64 + j] = v - m - logf(s);
}

extern "C" void kernel_launch(void* const* d_in, const int* in_sizes, int n_in,
                              void* d_out, int out_size, void* d_ws, size_t ws_size,
                              hipStream_t stream) {
    const float* x    = (const float*)d_in[0];
    const int*   ei   = (const int*)d_in[1];
    const float* W1   = (const float*)d_in[2];
    const float* b1   = (const float*)d_in[3];
    const float* W2   = (const float*)d_in[4];
    const float* b2   = (const float*)d_in[5];
    const float* temp = (const float*)d_in[6];
    float* out = (float*)d_out;

    char* ws = (char*)d_ws;
    size_t off = 0;
    auto alloc = [&](size_t bytes) -> void* {
        void* p = ws + off;
        off = (off + bytes + 255) & ~(size_t)255;
        return p;
    };
    int*    deg     = (int*)alloc((size_t)N_NODES * 4);
    float*  dinv    = (float*)alloc((size_t)N_NODES * 4);
    int*    row_ptr = (int*)alloc((size_t)(N_NODES + 1) * 4);
    int*    cursor  = (int*)alloc((size_t)N_NODES * 4);
    int*    partial = (int*)alloc((size_t)SCAN_B * 4);
    int*    bcursor = (int*)alloc((size_t)NBUCK * 4);
    int*    esrc    = (int*)alloc((size_t)(N_EDGES + N_NODES) * 4);
    __bf16* ubuf    = (__bf16*)alloc((size_t)NSL * (KHOPS + 1) * N_NODES * SW * 2); // 141MB
    __bf16* w1t     = (__bf16*)alloc((size_t)NFEAT * NHID * 2);
    __bf16* w2t     = (__bf16*)alloc((size_t)NHID * NCLASS * 2);
    size_t breg_bytes = (size_t)NBUCK * BCAP * 8;
    bool use_radix = (off + breg_bytes <= ws_size);
    int2* breg = use_radix ? (int2*)alloc(breg_bytes) : (int2*)0;

    zero_deg_kernel<<<(N_NODES + 255) / 256, 256, 0, stream>>>(deg, bcursor);
    if (use_radix) {
        radix1_kernel<<<(N_EDGES + TILE - 1) / TILE, 256, 0, stream>>>(ei, bcursor, breg);
        bucket_deg_kernel<<<NBUCK, 256, 0, stream>>>(breg, bcursor, deg, dinv);
        scan1_kernel<<<SCAN_B, 256, 0, stream>>>(deg, partial);
        scan2_kernel<<<1, 512, 0, stream>>>(partial);
        scan3_kernel<<<SCAN_B, 256, 0, stream>>>(deg, partial, row_ptr, cursor);
        radix2_kernel<<<NBUCK, 256, 0, stream>>>(breg, bcursor, row_ptr, esrc);
    } else {
        deg_kernel<<<(N_EDGES + 255) / 256, 256, 0, stream>>>(ei, deg);
        dinv_kernel<<<(N_NODES + 255) / 256, 256, 0, stream>>>(deg, dinv);
        scan1_kernel<<<SCAN_B, 256, 0, stream>>>(deg, partial);
        scan2_kernel<<<1, 512, 0, stream>>>(partial);
        scan3_kernel<<<SCAN_B, 256, 0, stream>>>(deg, partial, row_ptr, cursor);
        fill_kernel<<<(N_EDGES + N_NODES + 255) / 256, 256, 0, stream>>>(ei, cursor, esrc);
    }
    wprep_kernel<<<(NFEAT * NHID + NHID * NCLASS + 255) / 256, 256, 0, stream>>>(W1, W2, w1t, w2t);

    mlp_kernel<<<(N_NODES + MT - 1) / MT, 512, 0, stream>>>(x, w1t, b1, w2t, b2, dinv, ubuf);

    // slice-serialized propagation: all hops of slice s before slice s+1
    const size_t plane = (size_t)N_NODES * SW;            // 3.2MB plane (elements)
    const size_t sls   = (size_t)(KHOPS + 1) * plane;     // slice stride
    for (int s = 0; s < NSL; ++s) {
        for (int k = 0; k < KHOPS; ++k) {
            prop_kernel<<<N_NODES / 4, 256, 0, stream>>>(ubuf + (size_t)s * sls + (size_t)k * plane,
                                                         ubuf + (size_t)s * sls + (size_t)(k + 1) * plane,
                                                         row_ptr, esrc, dinv);
        }
    }

    finale_kernel<<<N_NODES / 4, 256, 0, stream>>>(ubuf, dinv, temp, out);
}

// Round 11
// 995.023 us; speedup vs baseline: 2.0294x; 2.0294x over previous
//
#include <hip/hip_runtime.h>

#define N_NODES 100000
#define N_EDGES 3200000
#define NFEAT 512
#define NHID 256
#define NCLASS 64
#define KHOPS 10
#define SCAN_B 391   // ceil(N_NODES/256)

// radix-partition CSR build
#define NBSHIFT 9
#define NBUCK 196    // ceil(N_NODES/512)
#define BCAP 20480   // >= max bucket size (avg 16.3K, sigma ~128)
#define TILE 4096

typedef __bf16 bf16x8 __attribute__((ext_vector_type(8)));
typedef __bf16 bf16x4 __attribute__((ext_vector_type(4)));
typedef float f32x4 __attribute__((ext_vector_type(4)));

// ---------------- preprocessing ----------------

__global__ __launch_bounds__(256) void zero_deg_kernel(int* __restrict__ deg, int* __restrict__ bcursor) {
    int i = blockIdx.x * 256 + threadIdx.x;
    if (i < N_NODES) deg[i] = 0;
    if (blockIdx.x == 0 && threadIdx.x < NBUCK) bcursor[threadIdx.x] = 0;
}

// fallback-path degree count (global atomics)
__global__ __launch_bounds__(256) void deg_kernel(const int* __restrict__ ei, int* __restrict__ deg) {
    int e = blockIdx.x * 256 + threadIdx.x;
    if (e < N_EDGES) atomicAdd(&deg[ei[N_EDGES + e]], 1);
}

__global__ __launch_bounds__(256) void dinv_kernel(const int* __restrict__ deg, float* __restrict__ dinv) {
    int i = blockIdx.x * 256 + threadIdx.x;
    if (i < N_NODES) dinv[i] = rsqrtf((float)(deg[i] + 1)); // +1 self-loop
}

// ---- radix pass 1: partition edges by dst>>9 with per-block contiguous runs ----

__global__ __launch_bounds__(256) void radix1_kernel(const int* __restrict__ ei,
                                                     int* __restrict__ bcursor,
                                                     int2* __restrict__ breg) {
    __shared__ int2 stage[TILE];
    __shared__ int hist[NBUCK];
    __shared__ int base[NBUCK];
    __shared__ int offs[NBUCK];
    int t = threadIdx.x;
    int e0 = blockIdx.x * TILE;
    int n = N_EDGES - e0; if (n > TILE) n = TILE;
    for (int i = t; i < NBUCK; i += 256) { hist[i] = 0; offs[i] = 0; }
    __syncthreads();
    for (int i = t; i < n; i += 256) {
        int s = ei[e0 + i];
        int d = ei[N_EDGES + e0 + i];
        stage[i] = make_int2(s, d);
        atomicAdd(&hist[d >> NBSHIFT], 1);
    }
    __syncthreads();
    for (int i = t; i < NBUCK; i += 256)
        if (hist[i]) base[i] = atomicAdd(&bcursor[i], hist[i]);
    __syncthreads();
    for (int i = t; i < n; i += 256) {
        int2 e = stage[i];
        int b = e.y >> NBSHIFT;
        int slot = base[b] + atomicAdd(&offs[b], 1);
        if (slot < BCAP) breg[(size_t)b * BCAP + slot] = e;
    }
}

// ---- per-bucket degree count in LDS (no global atomics) + fused dinv ----

__global__ __launch_bounds__(256) void bucket_deg_kernel(const int2* __restrict__ breg,
                                                         const int* __restrict__ bcursor,
                                                         int* __restrict__ deg,
                                                         float* __restrict__ dinv) {
    __shared__ int cnt[512];
    int b = blockIdx.x;
    int t = threadIdx.x;
    cnt[t] = 0; cnt[t + 256] = 0;
    __syncthreads();
    int n = bcursor[b]; if (n > BCAP) n = BCAP;
    const int2* bp = breg + (size_t)b * BCAP;
    for (int i = t; i < n; i += 256)
        atomicAdd(&cnt[bp[i].y & 511], 1);
    __syncthreads();
    int d0 = b << NBSHIFT;
    for (int j = t; j < 512; j += 256) {
        int i = d0 + j;
        if (i < N_NODES) {
            int d = cnt[j];
            deg[i] = d;
            dinv[i] = rsqrtf((float)(d + 1)); // +1 self-loop
        }
    }
}

// ---- hierarchical scan of (deg[i]+1) ----

__global__ __launch_bounds__(256) void scan1_kernel(const int* __restrict__ deg, int* __restrict__ partial) {
    __shared__ int red[256];
    int t = threadIdx.x;
    int i = blockIdx.x * 256 + t;
    red[t] = (i < N_NODES) ? deg[i] + 1 : 0;
    __syncthreads();
    for (int off = 128; off > 0; off >>= 1) {
        if (t < off) red[t] += red[t + off];
        __syncthreads();
    }
    if (t == 0) partial[blockIdx.x] = red[0];
}

__global__ __launch_bounds__(512) void scan2_kernel(int* __restrict__ partial) {
    __shared__ int s[512];
    int t = threadIdx.x;
    int v = (t < SCAN_B) ? partial[t] : 0;
    s[t] = v;
    __syncthreads();
    for (int off = 1; off < 512; off <<= 1) {
        int add = (t >= off) ? s[t - off] : 0;
        __syncthreads();
        s[t] += add;
        __syncthreads();
    }
    if (t < SCAN_B) partial[t] = s[t] - v; // exclusive
}

__global__ __launch_bounds__(256) void scan3_kernel(const int* __restrict__ deg,
                                                    const int* __restrict__ partial,
                                                    int* __restrict__ row_ptr,
                                                    int* __restrict__ cursor) {
    __shared__ int s[256];
    int t = threadIdx.x;
    int i = blockIdx.x * 256 + t;
    int v = (i < N_NODES) ? deg[i] + 1 : 0;
    s[t] = v;
    __syncthreads();
    for (int off = 1; off < 256; off <<= 1) {
        int add = (t >= off) ? s[t - off] : 0;
        __syncthreads();
        s[t] += add;
        __syncthreads();
    }
    int excl = s[t] - v + partial[blockIdx.x];
    if (i < N_NODES) {
        row_ptr[i] = excl;
        cursor[i] = excl;
        if (i == N_NODES - 1) row_ptr[N_NODES] = excl + v;
    }
}

// ---- radix pass 2: bucket -> final CSR via LDS cursors; self-loop at segment head ----

__global__ __launch_bounds__(256) void radix2_kernel(const int2* __restrict__ breg,
                                                     const int* __restrict__ bcursor,
                                                     const int* __restrict__ row_ptr,
                                                     int* __restrict__ esrc) {
    __shared__ int lcur[512];
    int b = blockIdx.x;
    int t = threadIdx.x;
    int d0 = b << NBSHIFT;
    int nn = N_NODES - d0; if (nn > 512) nn = 512;
    for (int j = t; j < nn; j += 256) {
        int rp = row_ptr[d0 + j];
        lcur[j] = rp + 1;
        esrc[rp] = d0 + j;        // self-loop
    }
    __syncthreads();
    int cnt = bcursor[b]; if (cnt > BCAP) cnt = BCAP;
    const int2* bp = breg + (size_t)b * BCAP;
    for (int i = t; i < cnt; i += 256) {
        int2 e = bp[i];
        int p = atomicAdd(&lcur[e.y - d0], 1);
        esrc[p] = e.x;
    }
}

// fallback CSR fill (used only if workspace too small for radix buffer)
__global__ __launch_bounds__(256) void fill_kernel(const int* __restrict__ ei,
                                                   int* __restrict__ cursor,
                                                   int* __restrict__ esrc) {
    int e = blockIdx.x * 256 + threadIdx.x;
    if (e < N_EDGES) {
        int s = ei[e], d = ei[N_EDGES + e];
        int p = atomicAdd(&cursor[d], 1);
        esrc[p] = s;
    } else if (e < N_EDGES + N_NODES) {
        int i = e - N_EDGES;
        int p = atomicAdd(&cursor[i], 1);
        esrc[p] = i; // self-loop
    }
}

// ---------------- weight prep: W1^T, W2^T in bf16 ----------------

__global__ __launch_bounds__(256) void wprep_kernel(const float* __restrict__ W1,
                                                    const float* __restrict__ W2,
                                                    __bf16* __restrict__ w1t,
                                                    __bf16* __restrict__ w2t) {
    int i = blockIdx.x * 256 + threadIdx.x;
    if (i < NFEAT * NHID) {
        int n = i >> 9, k = i & 511;           // w1t[n][k], k<512
        w1t[i] = (__bf16)W1[k * NHID + n];
    } else {
        int j = i - NFEAT * NHID;
        if (j < NHID * NCLASS) {
            int n = j >> 8, k = j & 255;       // w2t[n][k], k<256
            w2t[j] = (__bf16)W2[k * NCLASS + n];
        }
    }
}

// ---------------- fused MLP via bf16 MFMA — MT=128, 8 waves, staged + x-prefetch ----------------
// R5-proven structure; epilogue writes ONLY u0 = dinv .* h (taps deferred to finale).

#define MT 128
#define KC 64
#define XP 72
#define WP 72
#define HP 264

__global__ __launch_bounds__(512, 4) void mlp_kernel(const float* __restrict__ x,
                                                     const __bf16* __restrict__ w1t,
                                                     const float* __restrict__ b1,
                                                     const __bf16* __restrict__ w2t,
                                                     const float* __restrict__ b2,
                                                     const float* __restrict__ dinv,
                                                     __bf16* __restrict__ u0) {    // [N][64]
    __shared__ char smem[67584] __attribute__((aligned(16)));
    __bf16* xs  = (__bf16*)smem;              // 128*72*2 = 18432 B
    __bf16* wt  = (__bf16*)(smem + 18432);    // 256*72*2 = 36864 B
    __bf16* h1s = (__bf16*)smem;              // 128*264*2 = 67584 B (after barrier)

    int t = threadIdx.x;
    int wv = t >> 6, lane = t & 63;
    int lrow = lane & 15;
    int quad = lane >> 4;
    int row0 = blockIdx.x * MT;
    int wm = (wv >> 2) * 64;   // layer1 row group (0/64)
    int wn = (wv & 3) * 64;    // layer1 col group (0/64/128/192)

    // x staging map: j = it*512+t -> row r=j>>3 (0..127), col-octet c8=j&7
    const float* xpt[2];
    int xr[2], xc8[2];
    #pragma unroll
    for (int it = 0; it < 2; ++it) {
        int j = it * 512 + t;
        int r = j >> 3, c8 = j & 7;
        int rr = row0 + r; if (rr >= N_NODES) rr = N_NODES - 1;
        xpt[it] = &x[(size_t)rr * NFEAT + c8 * 8];
        xr[it] = r; xc8[it] = c8;
    }
    // prologue: prefetch chunk 0
    float4 px[4];
    px[0] = *(const float4*)(xpt[0]);
    px[1] = *(const float4*)(xpt[0] + 4);
    px[2] = *(const float4*)(xpt[1]);
    px[3] = *(const float4*)(xpt[1] + 4);

    f32x4 acc[4][4] = {};
    #pragma unroll 1
    for (int kc = 0; kc < NFEAT; kc += KC) {
        __syncthreads();   // previous chunk's frag reads done; LDS free
        // write prefetched x (cvt fp32->bf16) into xs
        #pragma unroll
        for (int it = 0; it < 2; ++it) {
            float4 v0 = px[it * 2], v1 = px[it * 2 + 1];
            bf16x8 o = { (__bf16)v0.x, (__bf16)v0.y, (__bf16)v0.z, (__bf16)v0.w,
                         (__bf16)v1.x, (__bf16)v1.y, (__bf16)v1.z, (__bf16)v1.w };
            *(bf16x8*)&xs[xr[it] * XP + xc8[it] * 8] = o;
        }
        // stage w1t chunk (L2-hot) directly
        #pragma unroll
        for (int it = 0; it < 4; ++it) {
            int j = it * 512 + t;
            int n = j >> 3, c8 = j & 7;
            *(bf16x8*)&wt[n * WP + c8 * 8] = *(const bf16x8*)&w1t[(size_t)n * NFEAT + kc + c8 * 8];
        }
        __syncthreads();   // chunk kc staged
        // prefetch next chunk's x (HBM latency hides under the MFMAs below)
        if (kc + KC < NFEAT) {
            px[0] = *(const float4*)(xpt[0] + kc + KC);
            px[1] = *(const float4*)(xpt[0] + kc + KC + 4);
            px[2] = *(const float4*)(xpt[1] + kc + KC);
            px[3] = *(const float4*)(xpt[1] + kc + KC + 4);
        }
        #pragma unroll
        for (int ks = 0; ks < 2; ++ks) {
            int kof = ks * 32 + quad * 8;
            bf16x8 a[4], b[4];
            #pragma unroll
            for (int mt = 0; mt < 4; ++mt)
                a[mt] = *(const bf16x8*)&xs[(wm + mt * 16 + lrow) * XP + kof];
            #pragma unroll
            for (int nt = 0; nt < 4; ++nt)
                b[nt] = *(const bf16x8*)&wt[(wn + nt * 16 + lrow) * WP + kof];
            #pragma unroll
            for (int mt = 0; mt < 4; ++mt)
                #pragma unroll
                for (int nt = 0; nt < 4; ++nt)
                    acc[mt][nt] = __builtin_amdgcn_mfma_f32_16x16x32_bf16(a[mt], b[nt], acc[mt][nt], 0, 0, 0);
        }
    }
    __syncthreads();   // K-loop done; staging buffers free for h1s
    // layer1 epilogue: bias + ReLU -> bf16 h1 in LDS
    #pragma unroll
    for (int nt = 0; nt < 4; ++nt) {
        int coln = wn + nt * 16 + lrow;
        float bb = b1[coln];
        #pragma unroll
        for (int mt = 0; mt < 4; ++mt) {
            int rbase = wm + mt * 16 + quad * 4;
            #pragma unroll
            for (int r = 0; r < 4; ++r) {
                float v = acc[mt][nt][r] + bb;
                h1s[(rbase + r) * HP + coln] = (__bf16)fmaxf(v, 0.f);
            }
        }
    }
    __syncthreads();
    // layer 2
    int rg = (wv >> 1) * 32;
    int cg = (wv & 1) * 32;
    f32x4 acc2[2][2] = {};
    #pragma unroll
    for (int ks = 0; ks < 8; ++ks) {
        int kof = ks * 32 + quad * 8;
        bf16x8 a2[2], bv[2];
        #pragma unroll
        for (int m2 = 0; m2 < 2; ++m2)
            a2[m2] = *(const bf16x8*)&h1s[(rg + m2 * 16 + lrow) * HP + kof];
        #pragma unroll
        for (int nt = 0; nt < 2; ++nt)
            bv[nt] = *(const bf16x8*)&w2t[(size_t)(cg + nt * 16 + lrow) * NHID + kof];
        #pragma unroll
        for (int m2 = 0; m2 < 2; ++m2)
            #pragma unroll
            for (int nt = 0; nt < 2; ++nt)
                acc2[m2][nt] = __builtin_amdgcn_mfma_f32_16x16x32_bf16(a2[m2], bv[nt], acc2[m2][nt], 0, 0, 0);
    }
    #pragma unroll
    for (int m2 = 0; m2 < 2; ++m2) {
        #pragma unroll
        for (int nt = 0; nt < 2; ++nt) {
            int coln = cg + nt * 16 + lrow;
            float bb = b2[coln];
            #pragma unroll
            for (int r = 0; r < 4; ++r) {
                int row = row0 + rg + m2 * 16 + quad * 4 + r;
                if (row < N_NODES) {
                    float v = acc2[m2][nt][r] + bb;
                    u0[(size_t)row * NCLASS + coln] = (__bf16)(dinv[row] * v);   // u = dinv .* h
                }
            }
        }
    }
}

// ---------------- propagation: full 128B row gathers in u-space, no tap RMW ----------------
// wave per dst node, 8 lanes/edge, dwordx4 gathers of u[src][0..63] (bf16);
// butterfly shfl_xor(8/16/32); lanes 0-7 apply dinv^2, write u_out. Taps deferred.

__global__ __launch_bounds__(256) void prop_kernel(const __bf16* __restrict__ uin,
                                                   __bf16* __restrict__ uout,
                                                   const int* __restrict__ row_ptr,
                                                   const int* __restrict__ esrc,
                                                   const float* __restrict__ dinv) {
    int node = blockIdx.x * 4 + (threadIdx.x >> 6);
    int lane = threadIdx.x & 63;
    int oct = lane >> 3, fi8 = lane & 7;
    int beg = row_ptr[node], end = row_ptr[node + 1];
    const uint4* urow = (const uint4*)uin; // node stride 8 uint4s (128B)
    float acc[8] = {};
    int nit = (end - beg + 7) >> 3;
    #pragma unroll 4
    for (int it = 0; it < nit; ++it) {
        int e = beg + it * 8 + oct;
        int ec = min(e, end - 1);       // clamp (self-loop => end>beg)
        int s = __builtin_nontemporal_load(&esrc[ec]);
        float m = (e < end) ? 1.f : 0.f;
        uint4 v = urow[(size_t)s * 8 + fi8];
        unsigned vv;
        vv = v.x;
        acc[0] = fmaf(m, __int_as_float(vv << 16), acc[0]);
        acc[1] = fmaf(m, __int_as_float(vv & 0xffff0000u), acc[1]);
        vv = v.y;
        acc[2] = fmaf(m, __int_as_float(vv << 16), acc[2]);
        acc[3] = fmaf(m, __int_as_float(vv & 0xffff0000u), acc[3]);
        vv = v.z;
        acc[4] = fmaf(m, __int_as_float(vv << 16), acc[4]);
        acc[5] = fmaf(m, __int_as_float(vv & 0xffff0000u), acc[5]);
        vv = v.w;
        acc[6] = fmaf(m, __int_as_float(vv << 16), acc[6]);
        acc[7] = fmaf(m, __int_as_float(vv & 0xffff0000u), acc[7]);
    }
    #pragma unroll
    for (int j = 0; j < 8; ++j) {
        acc[j] += __shfl_xor(acc[j], 8);
        acc[j] += __shfl_xor(acc[j], 16);
        acc[j] += __shfl_xor(acc[j], 32);
    }
    if (oct == 0) {
        float di = dinv[node];
        float d2 = di * di;
        union { __bf16 b[8]; uint4 u; } pk;
        #pragma unroll
        for (int j = 0; j < 8; ++j) pk.b[j] = (__bf16)(d2 * acc[j]);
        ((uint4*)uout)[(size_t)node * 8 + fi8] = pk.u;
    }
}

// ---------------- finale: deferred GPR taps + log_softmax, fused ----------------

__global__ __launch_bounds__(256) void finale_kernel(const __bf16* __restrict__ ubuf, // [K+1][N][64]
                                                     const float* __restrict__ dinv,
                                                     const float* __restrict__ temp,
                                                     float* __restrict__ out) {
    int node = blockIdx.x * 4 + (threadIdx.x >> 6);
    int j = threadIdx.x & 63;
    const unsigned short* ub = (const unsigned short*)ubuf;
    float acc = 0.f;
    #pragma unroll
    for (int k = 0; k <= KHOPS; ++k) {
        unsigned short us = __builtin_nontemporal_load(
            &ub[(size_t)k * N_NODES * NCLASS + (size_t)node * NCLASS + j]);
        acc = fmaf(temp[k], __int_as_float((unsigned)us << 16), acc);
    }
    float v = acc / dinv[node];   // h = u / dinv
    float m = v;
    #pragma unroll
    for (int o = 32; o > 0; o >>= 1) m = fmaxf(m, __shfl_xor(m, o));
    float ex = expf(v - m);
    float s = ex;
    #pragma unroll
    for (int o = 32; o > 0; o >>= 1) s += __shfl_xor(s, o);
    out[(size_t)node * 64 + j] = v - m - logf(s);
}

extern "C" void kernel_launch(void* const* d_in, const int* in_sizes, int n_in,
                              void* d_out, int out_size, void* d_ws, size_t ws_size,
                              hipStream_t stream) {
    const float* x    = (const float*)d_in[0];
    const int*   ei   = (const int*)d_in[1];
    const float* W1   = (const float*)d_in[2];
    const float* b1   = (const float*)d_in[3];
    const float* W2   = (const float*)d_in[4];
    const float* b2   = (const float*)d_in[5];
    const float* temp = (const float*)d_in[6];
    float* out = (float*)d_out;

    char* ws = (char*)d_ws;
    size_t off = 0;
    auto alloc = [&](size_t bytes) -> void* {
        void* p = ws + off;
        off = (off + bytes + 255) & ~(size_t)255;
        return p;
    };
    int*    deg     = (int*)alloc((size_t)N_NODES * 4);
    float*  dinv    = (float*)alloc((size_t)N_NODES * 4);
    int*    row_ptr = (int*)alloc((size_t)(N_NODES + 1) * 4);
    int*    cursor  = (int*)alloc((size_t)N_NODES * 4);
    int*    partial = (int*)alloc((size_t)SCAN_B * 4);
    int*    bcursor = (int*)alloc((size_t)NBUCK * 4);
    int*    esrc    = (int*)alloc((size_t)(N_EDGES + N_NODES) * 4);
    __bf16* ubuf    = (__bf16*)alloc((size_t)(KHOPS + 1) * N_NODES * NCLASS * 2); // 141MB
    __bf16* w1t     = (__bf16*)alloc((size_t)NFEAT * NHID * 2);
    __bf16* w2t     = (__bf16*)alloc((size_t)NHID * NCLASS * 2);
    size_t breg_bytes = (size_t)NBUCK * BCAP * 8;
    bool use_radix = (off + breg_bytes <= ws_size);
    int2* breg = use_radix ? (int2*)alloc(breg_bytes) : (int2*)0;

    zero_deg_kernel<<<(N_NODES + 255) / 256, 256, 0, stream>>>(deg, bcursor);
    if (use_radix) {
        radix1_kernel<<<(N_EDGES + TILE - 1) / TILE, 256, 0, stream>>>(ei, bcursor, breg);
        bucket_deg_kernel<<<NBUCK, 256, 0, stream>>>(breg, bcursor, deg, dinv);
        scan1_kernel<<<SCAN_B, 256, 0, stream>>>(deg, partial);
        scan2_kernel<<<1, 512, 0, stream>>>(partial);
        scan3_kernel<<<SCAN_B, 256, 0, stream>>>(deg, partial, row_ptr, cursor);
        radix2_kernel<<<NBUCK, 256, 0, stream>>>(breg, bcursor, row_ptr, esrc);
    } else {
        deg_kernel<<<(N_EDGES + 255) / 256, 256, 0, stream>>>(ei, deg);
        dinv_kernel<<<(N_NODES + 255) / 256, 256, 0, stream>>>(deg, dinv);
        scan1_kernel<<<SCAN_B, 256, 0, stream>>>(deg, partial);
        scan2_kernel<<<1, 512, 0, stream>>>(partial);
        scan3_kernel<<<SCAN_B, 256, 0, stream>>>(deg, partial, row_ptr, cursor);
        fill_kernel<<<(N_EDGES + N_NODES + 255) / 256, 256, 0, stream>>>(ei, cursor, esrc);
    }
    wprep_kernel<<<(NFEAT * NHID + NHID * NCLASS + 255) / 256, 256, 0, stream>>>(W1, W2, w1t, w2t);

    mlp_kernel<<<(N_NODES + MT - 1) / MT, 512, 0, stream>>>(x, w1t, b1, w2t, b2, dinv, ubuf);

    const size_t ustride = (size_t)N_NODES * NCLASS;
    for (int k = 0; k < KHOPS; ++k) {
        prop_kernel<<<N_NODES / 4, 256, 0, stream>>>(ubuf + (size_t)k * ustride,
                                                     ubuf + (size_t)(k + 1) * ustride,
                                                     row_ptr, esrc, dinv);
    }

    finale_kernel<<<N_NODES / 4, 256, 0, stream>>>(ubuf, dinv, temp, out);
}